// Round 11
// baseline (191.633 us; speedup 1.0000x reference)
//
#include <hip/hip_runtime.h>
#include <stdint.h>

#define BATCH 256
#define IN_F  1024
#define OUT_F 1024
#define RT    16      // row tiles (IN_F/64)
#define STN   16      // input bit-streams
#define NCOL  16384   // 16 (sg,s) groups * 1024 outputs

typedef int   v4i  __attribute__((ext_vector_type(4)));
typedef int   v16i __attribute__((ext_vector_type(16)));
typedef float v2f  __attribute__((ext_vector_type(2)));

// ws layout: Ap2 4MB | Bp 16MB | flags 2KB (16 sgs * 32 oq words)
#define AP_SZ ((size_t)STN * BATCH * IN_F)
#define BP_SZ ((size_t)64 * NCOL * 16)

// ---------------------------------------------------------------------------
// Fused prep.  Blocks 0..511: pack_B per (g,sg,o) + per-(sgs,oq,r) nonzero
// flags (32-col granularity).  Blocks 512..767: pack_A into per-(r,y) 32KB
// windows (fragment-linear: window = (r*8+y)*32768, chunk t*2048 + f*1024 +
// l*16) so cim can global_load_lds it with no swizzle.
// ---------------------------------------------------------------------------
__global__ __launch_bounds__(256) void pack_fused(
    const float* __restrict__ x, const float* __restrict__ w,
    uint8_t* __restrict__ Ap2, uint8_t* __restrict__ Bp,
    uint32_t* __restrict__ flags)
{
    if (blockIdx.x < 512) {
        int item = blockIdx.x * 256 + threadIdx.x;      // 131072 items
        int o  = item & 1023;
        int sg = (item >> 10) & 1;
        int g  = item >> 11;                            // 0..63
        int l  = threadIdx.x & 63;
        const float* wr = w + (size_t)o * IN_F + g * 16;
        uint32_t wq[16];
        #pragma unroll
        for (int j = 0; j < 16; ++j) {
            float wv = wr[j];
            float wf = rintf(fmaxf(sg ? -wv : wv, 0.0f) * 4096.0f);
            wq[j] = (uint32_t)fminf(wf, 65535.0f);
        }
        uint32_t nzmask = 0;
        #pragma unroll
        for (int s = 0; s < 8; ++s) {
            int sh = 14 - 2 * s;
            uint32_t dw[4], nz = 0;
            #pragma unroll
            for (int q = 0; q < 4; ++q) {
                uint32_t d = 0;
                #pragma unroll
                for (int j = 0; j < 4; ++j)
                    d |= ((wq[q * 4 + j] >> sh) & 3u) << (8 * j);
                dw[q] = d;
                nz |= d;
            }
            int sgs = sg * 8 + s;
            *(uint4*)(Bp + (size_t)(g * NCOL + sgs * 1024 + o) * 16) =
                make_uint4(dw[0], dw[1], dw[2], dw[3]);
            nzmask |= (nz ? 1u : 0u) << s;
        }
        int r = g >> 2;                                 // wave-uniform
        #pragma unroll
        for (int s = 0; s < 8; ++s) {
            unsigned long long bal = __ballot((int)((nzmask >> s) & 1u));
            uint32_t lo = (uint32_t)bal, hi = (uint32_t)(bal >> 32);
            int sgs = sg * 8 + s;
            if (l == 0 && lo)  atomicOr(&flags[sgs * 32 + (o >> 5)], 1u << r);
            if (l == 32 && hi) atomicOr(&flags[sgs * 32 + (o >> 5)], 1u << r);
        }
    } else {
        int item = (blockIdx.x - 512) * 256 + threadIdx.x;  // 65536 items
        int b  = item & 255;
        int tq = (item >> 8) & 3;
        int kg = item >> 10;                            // 0..63
        int r = kg >> 2, f = (kg >> 1) & 1, hi = kg & 1;
        int y = b >> 5, l = hi * 32 + (b & 31);
        const float* xr = x + (size_t)b * IN_F + kg * 16;
        uint32_t xu[16];
        #pragma unroll
        for (int j = 0; j < 16; ++j) {
            float xf = rintf(xr[j] * 4096.0f);          // round half-even
            xf = fminf(fmaxf(xf, -32768.0f), 32767.0f);
            xu[j] = (uint32_t)((int)xf) & 0xFFFFu;      // two's complement
        }
        uint8_t* wbase = Ap2 + ((size_t)(r * 8 + y) * 16) * 2048 + f * 1024 + l * 16;
        #pragma unroll
        for (int tt = 0; tt < 4; ++tt) {
            int t = tq * 4 + tt;
            uint32_t dw[4];
            #pragma unroll
            for (int q = 0; q < 4; ++q) {
                uint32_t d = 0;
                #pragma unroll
                for (int j = 0; j < 4; ++j)
                    d |= ((xu[q * 4 + j] >> t) & 1u) << (8 * j);
                dw[q] = d;
            }
            *(uint4*)(wbase + t * 2048) = make_uint4(dw[0], dw[1], dw[2], dw[3]);
        }
    }
}

// ---------------------------------------------------------------------------
// Main.  Block (oq,y) owns a 32-o x 32-b output region.  Active r set =
// union of this block's 16 per-sgs flag words.  Per r: double-buffered LDS
// staging of the 32KB A(r,y) window (global_load_lds, linear, no swizzle;
// stage r_next issued before computing r; ONE barrier per r).  Jobs (r,sgs)
// round-robin across the 8 waves.  A-frags from LDS (conflict-free
// ds_read_b128), B-frags direct global (L2).  ADC bits identical to verified
// R1-R10.  Reduction layout [w][i][lane]: conflict-free.  No atomics/fences.
// ---------------------------------------------------------------------------
__global__ __launch_bounds__(512) void cim_block(
    const uint8_t* __restrict__ Ap2, const uint8_t* __restrict__ Bp,
    const uint32_t* __restrict__ flags, const float* __restrict__ bias,
    float* __restrict__ out)
{
    __shared__ __align__(16) uint8_t Abuf[2][32768];    // 64 KB (red reuses)
    const float MAG = 12582912.0f;                      // 2^23 + 2^22
    int tid = threadIdx.x, wid = tid >> 6, l = tid & 63, h2 = l >> 5;
    int oq = blockIdx.x, y = blockIdx.y;

    // lane (l&15) holds the flag word of sgs=(l&15) for this oq
    uint32_t fw = flags[(l & 15) * 32 + oq];
    uint32_t rmask = fw;
    #pragma unroll
    for (int st = 1; st < 16; st <<= 1)
        rmask |= __shfl_xor(rmask, st, 64);             // block-uniform r set

    v2f acc2[8];
    #pragma unroll
    for (int i = 0; i < 8; ++i) acc2[i] = (v2f)0.0f;
    v16i zero;
    #pragma unroll
    for (int i = 0; i < 16; ++i) zero[i] = 0;

    // ---- stage helper pattern: 32 chunks of 1KB, 4 per wave ----
    #define STAGE(BUF, R)                                                     \
        do {                                                                  \
            const uint8_t* sbase = Ap2 + (size_t)((R) * 8 + y) * 32768;       \
            _Pragma("unroll")                                                 \
            for (int ii = 0; ii < 4; ++ii) {                                  \
                int chunk = wid * 4 + ii;                                     \
                __builtin_amdgcn_global_load_lds(                             \
                    (const __attribute__((address_space(1))) uint32_t*)       \
                        (sbase + chunk * 1024 + l * 16),                      \
                    (__attribute__((address_space(3))) uint32_t*)             \
                        (&Abuf[BUF][0] + chunk * 1024),                       \
                    16, 0, 0);                                                \
            }                                                                 \
        } while (0)

    int cnt = 0, cur = 0;
    uint32_t rm = rmask;
    if (rm) STAGE(0, __builtin_ctz(rm));
    __syncthreads();                                    // drain first stage

    while (rm) {
        int r = __builtin_ctz(rm);
        rm &= rm - 1;
        if (rm) STAGE(cur ^ 1, __builtin_ctz(rm));      // prefetch next r

        uint32_t smask = (uint32_t)__ballot((int)((fw >> r) & 1u)) & 0xFFFFu;
        while (smask) {                                 // block-uniform scan
            int sgs = __builtin_ctz(smask);
            smask &= smask - 1;
            if ((cnt++ & 7) != wid) continue;           // round-robin to waves

            int s = sgs & 7, sg = sgs >> 3;
            float clane = __int_as_float((141 - 2 * s) << 23) * (192.0f / 255.0f);
            if (sg) clane = -clane;                     // +-step * 4^(7-s)
            int col = sgs * 1024 + oq * 32 + (l & 31);

            v4i bf0 = *(const v4i*)(Bp + ((size_t)(r * 4 + h2)     * NCOL + col) * 16);
            v4i bf1 = *(const v4i*)(Bp + ((size_t)(r * 4 + 2 + h2) * NCOL + col) * 16);

            const uint8_t* abase = &Abuf[cur][0] + l * 16;
            #pragma unroll 4
            for (int t = 0; t < STN; ++t) {
                v4i af0 = *(const v4i*)(abase + t * 2048);
                v4i af1 = *(const v4i*)(abase + t * 2048 + 1024);
                v16i c = __builtin_amdgcn_mfma_i32_32x32x32_i8(af0, bf0, zero, 0, 0, 0);
                c      = __builtin_amdgcn_mfma_i32_32x32x32_i8(af1, bf1, c,    0, 0, 0);
                float wt = (t == 15) ? -32768.0f : (float)(1 << t);
                float cw = clane * wt;                  // exact pow2 scale
                #pragma unroll
                for (int i = 0; i < 8; ++i) {
                    v2f af; af.x = (float)c[2 * i]; af.y = (float)c[2 * i + 1];
                    v2f tq;
                    tq.x = fmaf(af.x, 1.328125f, MAG);  // exact prod; add rounds
                    tq.y = fmaf(af.y, 1.328125f, MAG);  //  half-even == rintf
                    v2f qf = tq - MAG;                  // Sterbenz-exact
                    acc2[i].x = fmaf(qf.x, cw, acc2[i].x);
                    acc2[i].y = fmaf(qf.y, cw, acc2[i].y);
                }
            }
            __asm__ volatile("" ::: "memory");          // keep loop shape
        }
        __syncthreads();                                // buf read + next stage done
        cur ^= 1;
    }

    // ---- wave partials -> LDS [w][i][lane] (conflict-free), reduce ----
    float* red = (float*)&Abuf[0][0];                   // reuse staging LDS
    __syncthreads();
    #pragma unroll
    for (int i = 0; i < 16; ++i) {
        float v = (i & 1) ? acc2[i >> 1].y : acc2[i >> 1].x;
        red[wid * 1024 + i * 64 + l] = v;
    }
    __syncthreads();
    #pragma unroll
    for (int k = 0; k < 2; ++k) {
        int i = wid * 2 + k;                            // 0..15
        float v = 0.0f;
        #pragma unroll
        for (int w8 = 0; w8 < 8; ++w8) v += red[w8 * 1024 + i * 64 + l];
        int b = y * 32 + (i & 3) + 8 * (i >> 2) + 4 * h2;   // C/D row map
        int o = oq * 32 + (l & 31);
        float ov = v * 0x1p-24f;
        float q = rintf(ov * 4096.0f);
        q = fminf(fmaxf(q, -32768.0f), 32767.0f);
        out[(size_t)b * OUT_F + o] = q * 0x1p-12f + bias[o];
    }
}

// ---------------------------------------------------------------------------
extern "C" void kernel_launch(void* const* d_in, const int* in_sizes, int n_in,
                              void* d_out, int out_size, void* d_ws, size_t ws_size,
                              hipStream_t stream) {
    const float* x    = (const float*)d_in[0];
    const float* w    = (const float*)d_in[1];
    const float* bias = (const float*)d_in[2];
    float* out = (float*)d_out;

    uint8_t*  Ap2   = (uint8_t*)d_ws;
    uint8_t*  Bp    = Ap2 + AP_SZ;
    uint32_t* flags = (uint32_t*)(Bp + BP_SZ);

    hipMemsetAsync(flags, 0, 512 * sizeof(uint32_t), stream);
    hipLaunchKernelGGL(pack_fused, dim3(768), dim3(256), 0, stream,
                       x, w, Ap2, Bp, flags);
    hipLaunchKernelGGL(cim_block, dim3(32, 8), dim3(512), 0, stream,
                       Ap2, Bp, flags, bias, out);
}

// Round 12
// 165.500 us; speedup vs baseline: 1.1579x; 1.1579x over previous
//
#include <hip/hip_runtime.h>
#include <stdint.h>

#define BATCH 256
#define IN_F  1024
#define OUT_F 1024
#define RT    16      // row tiles (IN_F/64)
#define STN   16      // input bit-streams
#define NCOL  16384   // 16 (sg,s) groups * 1024 outputs

typedef int   v4i  __attribute__((ext_vector_type(4)));
typedef int   v16i __attribute__((ext_vector_type(16)));
typedef float v2f  __attribute__((ext_vector_type(2)));

// ws layout: Ap2 4MB | Bp 16MB | flags 2KB (16 sgs * 32 oq words)
#define AP_SZ ((size_t)STN * BATCH * IN_F)
#define BP_SZ ((size_t)64 * NCOL * 16)

// ---------------------------------------------------------------------------
// Fused prep, read-coalesced.
// Blocks 0..511: pack_B, item = ((sg*1024+o)*64+g): lane-fast g -> wave reads
//   w[o][g*16..+16] as 4KB contiguous.  Writes scattered 16B (non-blocking).
//   Flags: one ballot per slice -> nibble-compress to 16-bit r-mask -> one
//   atomicOr per (wave, s).
// Blocks 512..767: pack_A, item = (b*256 + tq*64 + kg): lane-fast kg -> wave
//   reads x[b][kg*16..+16] as 4KB contiguous.  Writes into per-(r,y) 32KB
//   fragment-linear windows (chunk = t*2048 + f*1024 + l16*16).
// ---------------------------------------------------------------------------
__global__ __launch_bounds__(256) void pack_fused(
    const float* __restrict__ x, const float* __restrict__ w,
    uint8_t* __restrict__ Ap2, uint8_t* __restrict__ Bp,
    uint32_t* __restrict__ flags)
{
    if (blockIdx.x < 512) {
        int item = blockIdx.x * 256 + threadIdx.x;      // 131072 items
        int g  = item & 63;                             // lane-fast
        int o  = (item >> 6) & 1023;
        int sg = item >> 16;
        const float* wr = w + (size_t)o * IN_F + g * 16;
        uint32_t wq[16];
        #pragma unroll
        for (int j = 0; j < 16; ++j) {
            float wv = wr[j];
            float wf = rintf(fmaxf(sg ? -wv : wv, 0.0f) * 4096.0f);
            wq[j] = (uint32_t)fminf(wf, 65535.0f);
        }
        #pragma unroll
        for (int s = 0; s < 8; ++s) {
            int sh = 14 - 2 * s;
            uint32_t dw[4], nz = 0;
            #pragma unroll
            for (int q = 0; q < 4; ++q) {
                uint32_t d = 0;
                #pragma unroll
                for (int j = 0; j < 4; ++j)
                    d |= ((wq[q * 4 + j] >> sh) & 3u) << (8 * j);
                dw[q] = d;
                nz |= d;
            }
            int sgs = sg * 8 + s;
            *(uint4*)(Bp + (size_t)(g * NCOL + sgs * 1024 + o) * 16) =
                make_uint4(dw[0], dw[1], dw[2], dw[3]);
            // r-mask from ballot over g: bit r <- any of lanes 4r..4r+3
            unsigned long long bal = __ballot((int)(nz != 0));
            if ((threadIdx.x & 63) == 0 && bal) {
                unsigned long long t = bal | (bal >> 1);
                t |= t >> 2;
                t &= 0x1111111111111111ULL;
                uint32_t r16 = 0;
                #pragma unroll
                for (int i = 0; i < 16; ++i)
                    r16 |= (uint32_t)((t >> (4 * i)) & 1ULL) << i;
                atomicOr(&flags[sgs * 32 + (o >> 5)], r16);
            }
        }
    } else {
        int item = (blockIdx.x - 512) * 256 + threadIdx.x;  // 65536 items
        int kg = item & 63;                             // lane-fast
        int tq = (item >> 6) & 3;
        int b  = item >> 8;
        int r = kg >> 2, f = (kg >> 1) & 1, hi = kg & 1;
        int y = b >> 5, l16 = hi * 32 + (b & 31);
        const float* xr = x + (size_t)b * IN_F + kg * 16;
        uint32_t xu[16];
        #pragma unroll
        for (int j = 0; j < 16; ++j) {
            float xf = rintf(xr[j] * 4096.0f);          // round half-even
            xf = fminf(fmaxf(xf, -32768.0f), 32767.0f);
            xu[j] = (uint32_t)((int)xf) & 0xFFFFu;      // two's complement
        }
        uint8_t* wbase = Ap2 + ((size_t)(r * 8 + y) * 16) * 2048 + f * 1024 + l16 * 16;
        #pragma unroll
        for (int tt = 0; tt < 4; ++tt) {
            int t = tq * 4 + tt;
            uint32_t dw[4];
            #pragma unroll
            for (int q = 0; q < 4; ++q) {
                uint32_t d = 0;
                #pragma unroll
                for (int j = 0; j < 4; ++j)
                    d |= ((xu[q * 4 + j] >> t) & 1u) << (8 * j);
                dw[q] = d;
            }
            *(uint4*)(wbase + t * 2048) = make_uint4(dw[0], dw[1], dw[2], dw[3]);
        }
    }
}

// ---------------------------------------------------------------------------
// Main.  Block (oq,y) owns a 32-o x 32-b output region with 16 waves
// (1024 threads, 4 waves/SIMD).  Jobs (r,sgs) from 32-col flags, round-robin
// cnt&15 across waves, direct global A/B fragment loads (coalesced, L2-
// resident).  ADC bits identical to verified R1-R11.  LDS only for the final
// 16-slot conflict-free reduce + in-block ACM quantize + bias + final store.
// No barriers in the compute loop, no atomics, no fences.
// ---------------------------------------------------------------------------
__global__ __launch_bounds__(1024, 4) void cim_block(
    const uint8_t* __restrict__ Ap2, const uint8_t* __restrict__ Bp,
    const uint32_t* __restrict__ flags, const float* __restrict__ bias,
    float* __restrict__ out)
{
    __shared__ float red[16 * 1024];                    // 64 KB
    const float MAG = 12582912.0f;                      // 2^23 + 2^22
    int tid = threadIdx.x, wid = tid >> 6, l = tid & 63, h2 = l >> 5;
    int oq = blockIdx.x, y = blockIdx.y;

    // lane (l&15) holds the flag word of sgs=(l&15) for this oq
    uint32_t fw = flags[(l & 15) * 32 + oq];
    uint32_t rmask = fw;
    #pragma unroll
    for (int st = 1; st < 16; st <<= 1)
        rmask |= __shfl_xor(rmask, st, 64);             // wave-uniform r set

    v2f acc2[8];
    #pragma unroll
    for (int i = 0; i < 8; ++i) acc2[i] = (v2f)0.0f;
    v16i zero;
    #pragma unroll
    for (int i = 0; i < 16; ++i) zero[i] = 0;

    int cnt = 0;
    uint32_t rm = rmask;
    while (rm) {
        int r = __builtin_ctz(rm);
        rm &= rm - 1;
        uint32_t smask = (uint32_t)__ballot((int)((fw >> r) & 1u)) & 0xFFFFu;
        while (smask) {                                 // wave-uniform scan
            int sgs = __builtin_ctz(smask);
            smask &= smask - 1;
            if ((cnt++ & 15) != wid) continue;          // round-robin 16 waves

            int s = sgs & 7, sg = sgs >> 3;
            // clane = +-(192/255) * 2^(14-2s)
            float clane = __int_as_float((141 - 2 * s) << 23) * (192.0f / 255.0f);
            if (sg) clane = -clane;
            int col = sgs * 1024 + oq * 32 + (l & 31);

            v4i bf0 = *(const v4i*)(Bp + ((size_t)(r * 4 + h2)     * NCOL + col) * 16);
            v4i bf1 = *(const v4i*)(Bp + ((size_t)(r * 4 + 2 + h2) * NCOL + col) * 16);

            const uint8_t* abase = Ap2 + (size_t)(r * 8 + y) * 32768 + l * 16;
            #pragma unroll 4
            for (int t = 0; t < STN; ++t) {
                v4i af0 = *(const v4i*)(abase + t * 2048);
                v4i af1 = *(const v4i*)(abase + t * 2048 + 1024);
                v16i c = __builtin_amdgcn_mfma_i32_32x32x32_i8(af0, bf0, zero, 0, 0, 0);
                c      = __builtin_amdgcn_mfma_i32_32x32x32_i8(af1, bf1, c,    0, 0, 0);
                float wt = (t == 15) ? -32768.0f : (float)(1 << t);
                float cw = clane * wt;                  // exact pow2 scale
                #pragma unroll
                for (int i = 0; i < 8; ++i) {
                    v2f af; af.x = (float)c[2 * i]; af.y = (float)c[2 * i + 1];
                    v2f tq;
                    tq.x = fmaf(af.x, 1.328125f, MAG);  // exact prod; add rounds
                    tq.y = fmaf(af.y, 1.328125f, MAG);  //  half-even == rintf
                    v2f qf = tq - MAG;                  // Sterbenz-exact
                    acc2[i].x = fmaf(qf.x, cw, acc2[i].x);
                    acc2[i].y = fmaf(qf.y, cw, acc2[i].y);
                }
            }
        }
    }

    // ---- wave partials -> LDS [w][i*64+l] (conflict-free), reduce ----
    #pragma unroll
    for (int i = 0; i < 16; ++i) {
        float v = (i & 1) ? acc2[i >> 1].y : acc2[i >> 1].x;
        red[wid * 1024 + i * 64 + l] = v;
    }
    __syncthreads();
    {
        int i = wid;                                    // 0..15
        float v = 0.0f;
        #pragma unroll
        for (int w16 = 0; w16 < 16; ++w16) v += red[w16 * 1024 + i * 64 + l];
        int b = y * 32 + (i & 3) + 8 * (i >> 2) + 4 * h2;   // C/D row map
        int o = oq * 32 + (l & 31);
        float ov = v * 0x1p-24f;
        float q = rintf(ov * 4096.0f);
        q = fminf(fmaxf(q, -32768.0f), 32767.0f);
        out[(size_t)b * OUT_F + o] = q * 0x1p-12f + bias[o];
    }
}

// ---------------------------------------------------------------------------
extern "C" void kernel_launch(void* const* d_in, const int* in_sizes, int n_in,
                              void* d_out, int out_size, void* d_ws, size_t ws_size,
                              hipStream_t stream) {
    const float* x    = (const float*)d_in[0];
    const float* w    = (const float*)d_in[1];
    const float* bias = (const float*)d_in[2];
    float* out = (float*)d_out;

    uint8_t*  Ap2   = (uint8_t*)d_ws;
    uint8_t*  Bp    = Ap2 + AP_SZ;
    uint32_t* flags = (uint32_t*)(Bp + BP_SZ);

    hipMemsetAsync(flags, 0, 512 * sizeof(uint32_t), stream);
    hipLaunchKernelGGL(pack_fused, dim3(768), dim3(256), 0, stream,
                       x, w, Ap2, Bp, flags);
    hipLaunchKernelGGL(cim_block, dim3(32, 8), dim3(1024), 0, stream,
                       Ap2, Bp, flags, bias, out);
}

// Round 13
// 164.192 us; speedup vs baseline: 1.1671x; 1.0080x over previous
//
#include <hip/hip_runtime.h>
#include <stdint.h>

#define BATCH 256
#define IN_F  1024
#define OUT_F 1024
#define RT    16      // row tiles (IN_F/64)
#define STN   16      // input bit-streams
#define NCOL  16384   // 16 (sg,s) groups * 1024 outputs

typedef int   v4i  __attribute__((ext_vector_type(4)));
typedef float v2f  __attribute__((ext_vector_type(2)));

// ws layout: Ap2 4MB | Bp 16MB | rmask 64KB (16 sgs * 1024 o words)
#define AP_SZ ((size_t)STN * BATCH * IN_F)
#define BP_SZ ((size_t)64 * NCOL * 16)

// ---------------------------------------------------------------------------
// Fused prep (R12's read-coalesced form, atomics/memset eliminated).
// Blocks 0..511: pack_B, item=((sg*1024+o)*64+g), lane-fast g: wave reads one
//   w-row 4KB contiguous; per s, ballot over g gives the FULL 16-bit r-mask
//   for (sgs,o) in one wave -> lane0 stores rmask[sgs*1024+o] directly.
// Blocks 512..767: pack_A, item=(b*256+tq*64+kg), lane-fast kg: coalesced
//   x-row reads; writes per-(r,y32) 32KB fragment-linear windows.
// ---------------------------------------------------------------------------
__global__ __launch_bounds__(256) void pack_fused(
    const float* __restrict__ x, const float* __restrict__ w,
    uint8_t* __restrict__ Ap2, uint8_t* __restrict__ Bp,
    uint32_t* __restrict__ rmask)
{
    if (blockIdx.x < 512) {
        int item = blockIdx.x * 256 + threadIdx.x;      // 131072 items
        int g  = item & 63;                             // lane-fast
        int o  = (item >> 6) & 1023;
        int sg = item >> 16;
        const float* wr = w + (size_t)o * IN_F + g * 16;
        uint32_t wq[16];
        #pragma unroll
        for (int j = 0; j < 16; ++j) {
            float wv = wr[j];
            float wf = rintf(fmaxf(sg ? -wv : wv, 0.0f) * 4096.0f);
            wq[j] = (uint32_t)fminf(wf, 65535.0f);
        }
        #pragma unroll
        for (int s = 0; s < 8; ++s) {
            int sh = 14 - 2 * s;
            uint32_t dw[4], nz = 0;
            #pragma unroll
            for (int q = 0; q < 4; ++q) {
                uint32_t d = 0;
                #pragma unroll
                for (int j = 0; j < 4; ++j)
                    d |= ((wq[q * 4 + j] >> sh) & 3u) << (8 * j);
                dw[q] = d;
                nz |= d;
            }
            int sgs = sg * 8 + s;
            *(uint4*)(Bp + (size_t)(g * NCOL + sgs * 1024 + o) * 16) =
                make_uint4(dw[0], dw[1], dw[2], dw[3]);
            // full r-mask for (sgs,o): bit r <- any nz among lanes g=4r..4r+3
            unsigned long long bal = __ballot((int)(nz != 0));
            if ((threadIdx.x & 63) == 0) {
                unsigned long long t = bal | (bal >> 1);
                t |= t >> 2;
                t &= 0x1111111111111111ULL;
                uint32_t r16 = 0;
                #pragma unroll
                for (int i = 0; i < 16; ++i)
                    r16 |= (uint32_t)((t >> (4 * i)) & 1ULL) << i;
                rmask[sgs * 1024 + o] = r16;            // non-atomic, owned
            }
        }
    } else {
        int item = (blockIdx.x - 512) * 256 + threadIdx.x;  // 65536 items
        int kg = item & 63;                             // lane-fast
        int tq = (item >> 6) & 3;
        int b  = item >> 8;
        int r = kg >> 2, f = (kg >> 1) & 1, hi = kg & 1;
        int y = b >> 5, l16 = hi * 32 + (b & 31);
        const float* xr = x + (size_t)b * IN_F + kg * 16;
        uint32_t xu[16];
        #pragma unroll
        for (int j = 0; j < 16; ++j) {
            float xf = rintf(xr[j] * 4096.0f);          // round half-even
            xf = fminf(fmaxf(xf, -32768.0f), 32767.0f);
            xu[j] = (uint32_t)((int)xf) & 0xFFFFu;      // two's complement
        }
        uint8_t* wbase = Ap2 + ((size_t)(r * 8 + y) * 16) * 2048 + f * 1024 + l16 * 16;
        #pragma unroll
        for (int tt = 0; tt < 4; ++tt) {
            int t = tq * 4 + tt;
            uint32_t dw[4];
            #pragma unroll
            for (int q = 0; q < 4; ++q) {
                uint32_t d = 0;
                #pragma unroll
                for (int j = 0; j < 4; ++j)
                    d |= ((xu[q * 4 + j] >> t) & 1u) << (8 * j);
                dw[q] = d;
            }
            *(uint4*)(wbase + t * 2048) = make_uint4(dw[0], dw[1], dw[2], dw[3]);
        }
    }
}

// ---------------------------------------------------------------------------
// Main.  Block (oq,yb) owns a 16-o x 16-b region; 512 threads = 8 waves,
// grid (64,16) = 1024 blocks -> 4 blocks/CU x 8 waves = 8 waves/SIMD.
// MFMA 16x16x64 i8: one B-frag v4i per job (t-invariant), one A-frag v4i
// per t, 4 f32 C per lane.  Jobs (r,sgs) from the per-o rmask table ORed
// over the block's 16 o's; round-robin cnt&7 across waves.  ADC bits
// identical to verified R1-R12.  8KB LDS reduce, direct final store.
// ---------------------------------------------------------------------------
__global__ __launch_bounds__(512, 8) void cim16(
    const uint8_t* __restrict__ Ap2, const uint8_t* __restrict__ Bp,
    const uint32_t* __restrict__ rmask, const float* __restrict__ bias,
    float* __restrict__ out)
{
    __shared__ float red[8 * 256];                      // 8 KB
    const float MAG = 12582912.0f;                      // 2^23 + 2^22
    int tid = threadIdx.x, wid = tid >> 6, l = tid & 63;
    int oq = blockIdx.x, yb = blockIdx.y;
    int y32 = yb >> 1, h = yb & 1;
    int kg = l >> 4, cl = l & 15;

    // fw[sgs = l&15] = OR of rmask over this block's 16 o's
    const uint4* rm4 = (const uint4*)(rmask + (l & 15) * 1024 + oq * 16);
    uint4 m0 = rm4[0], m1 = rm4[1], m2 = rm4[2], m3 = rm4[3];
    uint32_t fw = m0.x | m0.y | m0.z | m0.w | m1.x | m1.y | m1.z | m1.w
                | m2.x | m2.y | m2.z | m2.w | m3.x | m3.y | m3.z | m3.w;
    uint32_t rmu = fw;
    #pragma unroll
    for (int st = 1; st < 16; st <<= 1)
        rmu |= __shfl_xor(rmu, st, 64);                 // union over sgs

    // per-lane constant A offset within a (r,y32) window
    int aoff = (kg >> 1) * 1024 + ((kg & 1) * 32 + h * 16 + cl) * 16;

    v2f acc2[2];
    acc2[0] = (v2f)0.0f; acc2[1] = (v2f)0.0f;
    v4i zero4;
    zero4[0] = 0; zero4[1] = 0; zero4[2] = 0; zero4[3] = 0;

    int cnt = 0;
    uint32_t rm = rmu;
    while (rm) {
        int r = __builtin_ctz(rm);
        rm &= rm - 1;
        uint32_t smask = (uint32_t)__ballot((int)((fw >> r) & 1u)) & 0xFFFFu;
        while (smask) {                                 // wave-uniform scan
            int sgs = __builtin_ctz(smask);
            smask &= smask - 1;
            if ((cnt++ & 7) != wid) continue;           // round-robin 8 waves

            int s = sgs & 7, sg = sgs >> 3;
            // clane = +-(192/255) * 2^(14-2s)
            float clane = __int_as_float((141 - 2 * s) << 23) * (192.0f / 255.0f);
            if (sg) clane = -clane;

            v4i bf = *(const v4i*)(Bp +
                ((size_t)(r * 4 + kg) * NCOL + sgs * 1024 + oq * 16 + cl) * 16);
            const uint8_t* ab = Ap2 + (size_t)(r * 8 + y32) * 32768 + aoff;

            #pragma unroll 4
            for (int t = 0; t < STN; ++t) {
                v4i af = *(const v4i*)(ab + t * 2048);
                v4i c = __builtin_amdgcn_mfma_i32_16x16x64_i8(af, bf, zero4, 0, 0, 0);
                float wt = (t == 15) ? -32768.0f : (float)(1 << t);
                float cw = clane * wt;                  // exact pow2 scale
                #pragma unroll
                for (int i = 0; i < 2; ++i) {
                    v2f af2; af2.x = (float)c[2 * i]; af2.y = (float)c[2 * i + 1];
                    v2f tq;
                    tq.x = fmaf(af2.x, 1.328125f, MAG); // exact prod; add rounds
                    tq.y = fmaf(af2.y, 1.328125f, MAG); //  half-even == rintf
                    v2f qf = tq - MAG;                  // Sterbenz-exact
                    acc2[i].x = fmaf(qf.x, cw, acc2[i].x);
                    acc2[i].y = fmaf(qf.y, cw, acc2[i].y);
                }
            }
        }
    }

    // ---- 8-wave reduce in LDS (conflict-free), quantize, store ----
    #pragma unroll
    for (int i = 0; i < 4; ++i) {
        float v = (i & 1) ? acc2[i >> 1].y : acc2[i >> 1].x;
        red[wid * 256 + i * 64 + l] = v;
    }
    __syncthreads();
    if (tid < 256) {
        int le = tid & 63, ie = tid >> 6;
        float v = 0.0f;
        #pragma unroll
        for (int w8 = 0; w8 < 8; ++w8) v += red[w8 * 256 + ie * 64 + le];
        int row = (le >> 4) * 4 + ie;                   // C/D 16x16 row map
        int o = oq * 16 + (le & 15);
        float ov = v * 0x1p-24f;
        float q = rintf(ov * 4096.0f);
        q = fminf(fmaxf(q, -32768.0f), 32767.0f);
        out[(size_t)(yb * 16 + row) * OUT_F + o] = q * 0x1p-12f + bias[o];
    }
}

// ---------------------------------------------------------------------------
extern "C" void kernel_launch(void* const* d_in, const int* in_sizes, int n_in,
                              void* d_out, int out_size, void* d_ws, size_t ws_size,
                              hipStream_t stream) {
    const float* x    = (const float*)d_in[0];
    const float* w    = (const float*)d_in[1];
    const float* bias = (const float*)d_in[2];
    float* out = (float*)d_out;

    uint8_t*  Ap2   = (uint8_t*)d_ws;
    uint8_t*  Bp    = Ap2 + AP_SZ;
    uint32_t* rmask = (uint32_t*)(Bp + BP_SZ);

    hipLaunchKernelGGL(pack_fused, dim3(768), dim3(256), 0, stream,
                       x, w, Ap2, Bp, rmask);
    hipLaunchKernelGGL(cim16, dim3(64, 16), dim3(512), 0, stream,
                       Ap2, Bp, rmask, bias, out);
}